// Round 3
// baseline (242.201 us; speedup 1.0000x reference)
//
#include <hip/hip_runtime.h>

#define H 512
#define WID 1024
#define HW (H*WID)
#define B 4
#define K 8
#define NB 1024

// ws layout in 4-byte words
#define OFF_LOSS  0
#define OFF_STATS 16                      // B*K*5 = 160 floats: cnt,sx,sy,ss,ss2
#define OFF_FIN   (OFF_STATS + B*K*5)     // B*K*4 floats: cx,cy,negsexp,cnt
#define OFF_CNTG  (OFF_FIN + B*K*4)       // B*K*NB u32
#define OFF_POSG  (OFF_CNTG + B*K*NB)     // B*K*NB u32
#define TOTAL_WORDS (OFF_POSG + B*K*NB)

static __device__ __forceinline__ float frcp(float x){
#if __has_builtin(__builtin_amdgcn_rcpf)
  return __builtin_amdgcn_rcpf(x);
#else
  return 1.0f / x;
#endif
}
// tanh(x) = 1 - 2/(e^{2x}+1); saturates correctly for |x| large
static __device__ __forceinline__ float ftanh(float x){
  return 1.0f - 2.0f * frcp(__expf(2.0f*x) + 1.0f);
}
static __device__ __forceinline__ float fsigmoid(float x){
  return frcp(1.0f + __expf(-x));
}

// ---------------- Kernel 1: per-(b,k) mask statistics (wave-per-k) ----------------
// Block = 512 threads = 8 waves; wave w accumulates only k = w+1 (5 accumulators,
// no spill). Branchless, int4/float4 vectorized, unconditional loads so the
// compiler software-pipelines. 128 blocks/b -> 2 blocks/CU -> 16 waves/CU.
__global__ __launch_bounds__(512) void k1_stats(const float* __restrict__ pred,
                                                const int* __restrict__ inst,
                                                float* __restrict__ ws) {
  const int b = blockIdx.y;
  const int wv   = threadIdx.x >> 6;      // 0..7
  const int lane = threadIdx.x & 63;
  const int kk   = wv + 1;                // instance id this wave owns
  const float4* sig4 = (const float4*)(pred + (size_t)(8*b + 5) * HW);  // ch2 t=1
  const int4*   ins4 = (const int4*)(inst + (size_t)(2*b + 1) * HW);
  const int CH4   = HW / (128*4);         // 1024 int4-groups per block
  const int base4 = blockIdx.x * CH4;
  float cnt=0.f, sx=0.f, sy=0.f, ss=0.f, ss2=0.f;
  for (int q = lane; q < CH4; q += 64) {
    const int4   iv = ins4[base4 + q];
    const float4 sv = sig4[base4 + q];
    const int p = (base4 + q) * 4;        // p%4==0, W=1024 -> same row for 4 elems
    const float xm0 = (float)(p & (WID-1)) * (2.0f/2047.0f);
    const float ym  = (float)(p >> 10)     * (1.0f/1023.0f);
    const float m0 = (iv.x==kk)?1.f:0.f, m1=(iv.y==kk)?1.f:0.f,
                m2 = (iv.z==kk)?1.f:0.f, m3=(iv.w==kk)?1.f:0.f;
    cnt += (m0+m1)+(m2+m3);
    sx  += m0*xm0 + m1*(xm0+1.0f*(2.0f/2047.0f)) + m2*(xm0+2.0f*(2.0f/2047.0f)) + m3*(xm0+3.0f*(2.0f/2047.0f));
    sy  += ((m0+m1)+(m2+m3))*ym;
    ss  += m0*sv.x + m1*sv.y + m2*sv.z + m3*sv.w;
    ss2 += m0*sv.x*sv.x + m1*sv.y*sv.y + m2*sv.z*sv.z + m3*sv.w*sv.w;
  }
  #pragma unroll
  for (int o=1;o<64;o<<=1){
    cnt+=__shfl_xor(cnt,o,64);
    sx +=__shfl_xor(sx, o,64);
    sy +=__shfl_xor(sy, o,64);
    ss +=__shfl_xor(ss, o,64);
    ss2+=__shfl_xor(ss2,o,64);
  }
  if (lane == 0) {
    float* st = ws + OFF_STATS + (b*K + wv)*5;
    atomicAdd(st+0, cnt);
    atomicAdd(st+1, sx);
    atomicAdd(st+2, sy);
    atomicAdd(st+3, ss);
    atomicAdd(st+4, ss2);
  }
}

// ---------------- Kernel 2: finalize stats + var loss ----------------
__global__ void k2_fin(float* __restrict__ ws) {
  const int t = threadIdx.x;
  if (t >= B*K) return;
  const float* st = ws + OFF_STATS + t*5;
  const float cnt = st[0], sx = st[1], sy = st[2], ss = st[3], ss2 = st[4];
  const float present = (cnt > 0.0f) ? 1.0f : 0.0f;
  const float safe = fmaxf(cnt, 1.0f);
  const float cx = sx/safe, cy = sy/safe, sm = ss/safe;
  const float var = (ss2 - 2.0f*sm*ss + sm*sm*cnt)/safe;   // N_SIGMA=1
  const float sexp = expf(10.0f * sm);
  float* fin = ws + OFF_FIN + t*4;
  fin[0]=cx; fin[1]=cy; fin[2]=-sexp; fin[3]=cnt;
  // W_VAR=10, /(B-1)=3
  atomicAdd(ws + OFF_LOSS, present * 10.0f * var * (1.0f/3.0f));
}

// ---------------- Kernel 3: main pass — histograms + seed/bg loss ----------------
// 256 blocks/b -> 4 blocks/CU (128 KiB LDS) -> 16 waves/CU.
__global__ __launch_bounds__(256) void k3_main(const float* __restrict__ pred,
                                               const int* __restrict__ inst,
                                               float* __restrict__ ws) {
  const int b = blockIdx.y;
  __shared__ unsigned int hist[K*NB];           // pos<<16 | cnt, 32 KiB
  __shared__ float4 finL[K];                    // {cx, cy, -sexp, cnt}
  for (int i = threadIdx.x; i < K*NB; i += 256) hist[i] = 0;
  if (threadIdx.x < K) {
    const float* fin = ws + OFF_FIN + (b*K + threadIdx.x)*4;
    finL[threadIdx.x] = make_float4(fin[0], fin[1], fin[2], fin[3]);
  }
  __syncthreads();
  const float* p0 = pred + (size_t)(8*b+1)*HW;  // ch0 t=1
  const float* p1 = pred + (size_t)(8*b+3)*HW;  // ch1 t=1
  const float* p3 = pred + (size_t)(8*b+7)*HW;  // ch3 t=1
  const int*   ins = inst + (size_t)(2*b+1)*HW;
  const int lane = threadIdx.x & 63;
  float sAcc = 0.0f;                            // bg seed^2 + sum_k m*(seed-dist)^2
  const int CH = HW/256;                        // 2048 px/block
  const int start = blockIdx.x * CH;
  for (int q = threadIdx.x; q < CH; q += 256) {
    const int p = start + q;
    const int iv = ins[p];
    const float sex = ftanh(p0[p]) + (float)(p & (WID-1)) * (2.0f/2047.0f);
    const float sey = ftanh(p1[p]) + (float)(p >> 10)     * (1.0f/1023.0f);
    const float sd  = fsigmoid(p3[p]);
    if (iv == 0) sAcc += sd*sd;
    // lane-rotated k order: the wave's 64 lanes hit 8 different k-histograms
    // at any instant -> same-address atomic degree <= 8.
    #pragma unroll
    for (int j=0;j<K;j++){
      const int k = (j + lane) & (K-1);
      const float4 f = finL[k];
      const float dx = sex - f.x;
      const float dy = sey - f.y;
      const float dist = __expf(f.z*(dx*dx + dy*dy));  // in (0,1]
      const bool own = (iv == k+1);
      float e;
      if (own) { const float d = sd - dist; sAcc += d*d; e = 2.0f - 2.0f*dist; }
      else     { e = 2.0f*dist; }
      int bu = (int)(e * (NB*0.5f));
      if (bu > NB-1) bu = NB-1;
      atomicAdd(&hist[k*NB + bu], own ? 0x10001u : 1u);
    }
  }
  __syncthreads();
  unsigned int* wsu  = (unsigned int*)ws;
  unsigned int* cntG = wsu + OFF_CNTG + b*K*NB;
  unsigned int* posG = wsu + OFF_POSG + b*K*NB;
  for (int i = threadIdx.x; i < K*NB; i += 256) {
    const unsigned int v = hist[i];
    if (v) {
      atomicAdd(&cntG[i], v & 0xFFFFu);
      const unsigned int pz = v >> 16;
      if (pz) atomicAdd(&posG[i], pz);
    }
  }
  #pragma unroll
  for (int o=1;o<64;o<<=1) sAcc += __shfl_xor(sAcc, o, 64);
  __shared__ float wsum[4];
  if ((threadIdx.x & 63) == 0) wsum[threadIdx.x>>6] = sAcc;
  __syncthreads();
  if (threadIdx.x == 0) {
    const float tot = wsum[0]+wsum[1]+wsum[2]+wsum[3];
    // W_SEED=1, /npix, /(B-1)
    atomicAdd(ws + OFF_LOSS, tot * (1.0f/((float)HW * 3.0f)));
  }
}

// ---------------- Kernel 4: Lovász hinge from histograms ----------------
__global__ __launch_bounds__(256) void k4_lovasz(float* __restrict__ ws) {
  const int bk = blockIdx.x;                    // b*K + k
  const unsigned int* wsu  = (const unsigned int*)ws;
  const unsigned int* cntG = wsu + OFF_CNTG + bk*NB;
  const unsigned int* posG = wsu + OFF_POSG + bk*NB;
  const float cntF = ws[OFF_FIN + bk*4 + 3];
  if (cntF <= 0.0f) return;                     // present = 0
  const double Pd = (double)cntF;
  const int t = threadIdx.x;
  const int CHNK = NB/256;                      // 4 buckets per thread
  unsigned int mc[NB/256], mp[NB/256];
  int lc = 0, lp = 0;
  #pragma unroll
  for (int j=0;j<CHNK;j++){
    const int bu = NB-1 - (t*CHNK + j);         // descending error order
    mc[j] = cntG[bu]; mp[j] = posG[bu];
    lc += (int)mc[j]; lp += (int)mp[j];
  }
  __shared__ int sc[256], sp[256], ec[256], ep[256];
  sc[t]=lc; sp[t]=lp;
  __syncthreads();
  if (t==0){
    int a=0,c=0;
    for(int i=0;i<256;i++){ ec[i]=a; ep[i]=c; a+=sc[i]; c+=sp[i]; }
  }
  __syncthreads();
  int irun = ec[t], crun = ep[t];
  double acc = 0.0;
  #pragma unroll
  for (int j=0;j<CHNK;j++){
    const int bu = NB-1 - (t*CHNK + j);
    const int n = (int)mc[j];
    if (n) {
      const double jac0 = (irun==0) ? 0.0 : 1.0 - (Pd - crun)/(Pd + irun - crun);
      irun += n; crun += (int)mp[j];
      const double jac1 = 1.0 - (Pd - crun)/(Pd + irun - crun);
      acc += ((bu + 0.5) * (2.0/NB)) * (jac1 - jac0);
    }
  }
  __shared__ double racc[256];
  racc[t] = acc;
  __syncthreads();
  if (t==0){
    double tot=0.0;
    for (int i=0;i<256;i++) tot += racc[i];
    atomicAdd(ws + OFF_LOSS, (float)(tot * (1.0/3.0)));  // W_INST=1, /(B-1)
  }
}

// ---------------- Kernel 5: write output ----------------
__global__ void k5_out(const float* __restrict__ ws, float* __restrict__ out) {
  if (threadIdx.x == 0) out[0] = ws[OFF_LOSS];
}

extern "C" void kernel_launch(void* const* d_in, const int* in_sizes, int n_in,
                              void* d_out, int out_size, void* d_ws, size_t ws_size,
                              hipStream_t stream) {
  const float* pred = (const float*)d_in[0];
  const int*   inst = (const int*)d_in[1];
  float* ws  = (float*)d_ws;
  float* out = (float*)d_out;
  hipMemsetAsync(d_ws, 0, (size_t)TOTAL_WORDS*4, stream);
  k1_stats<<<dim3(128,B), 512, 0, stream>>>(pred, inst, ws);
  k2_fin  <<<1, 64, 0, stream>>>(ws);
  k3_main <<<dim3(256,B), 256, 0, stream>>>(pred, inst, ws);
  k4_lovasz<<<B*K, 256, 0, stream>>>(ws);
  k5_out  <<<1, 64, 0, stream>>>(ws, out);
}